// Round 1
// baseline (160.804 us; speedup 1.0000x reference)
//
#include <hip/hip_runtime.h>
#include <hip/hip_fp16.h>

#define N_CELLS 50000
#define DEG 32
#define DIM 64
#define NEG_SLOPE 0.2
#define NPAIRS (N_CELLS / 2)

// Kernel A:
//  (1) ns[r] = x[r].(W0@a_src), nd[r] = x[r].(W0@a_dst) in f64 (row_sum
//      cancellation amplifies ~1e4x -> f64 required on the sums). Byte-identical
//      summation order to the previously-passing kernel.
//  (2) NEW: message = x @ W0, stored fp16 (6.4 MB) for the edge-kernel gathers.
//      Linearity: sum_e w_e*(x[col_e]@W0) == (sum_e w_e*x[col_e])@W0 — we now
//      precompute the left side's inner term so the edge kernel needs NO W0
//      multiply (removes 128 fma + 16 ds_read_b128 per iter AND the 64-VGPR
//      w0c[] column cache that capped occupancy at 4 waves/SIMD).
__global__ __launch_bounds__(256, 4)
void gat_prep(const float* __restrict__ x,
              const float* __restrict__ W0,
              const float* __restrict__ a0,
              __half* __restrict__ m2,
              double* __restrict__ ns,
              double* __restrict__ nd) {
  __shared__ double2 p_s[DIM];       // (p_src[i], p_dst[i])
  __shared__ float x_s[4][DIM];      // per-wave row slot for message GEMV

  const int tid = threadIdx.x;
  const int lane = tid & 63;
  const int wid = tid >> 6;

  if (tid < DIM) {
    double ps = 0.0, pd = 0.0;
    const float4* w4 = (const float4*)(W0 + tid * DIM);
#pragma unroll
    for (int q = 0; q < DIM / 4; ++q) {
      float4 w = w4[q];
      ps = fma((double)w.x, (double)a0[4 * q + 0], ps);
      ps = fma((double)w.y, (double)a0[4 * q + 1], ps);
      ps = fma((double)w.z, (double)a0[4 * q + 2], ps);
      ps = fma((double)w.w, (double)a0[4 * q + 3], ps);
      pd = fma((double)w.x, (double)a0[DIM + 4 * q + 0], pd);
      pd = fma((double)w.y, (double)a0[DIM + 4 * q + 1], pd);
      pd = fma((double)w.z, (double)a0[DIM + 4 * q + 2], pd);
      pd = fma((double)w.w, (double)a0[DIM + 4 * q + 3], pd);
    }
    p_s[tid] = make_double2(ps, pd);
  }

  // W0 column `lane` in registers (coalesced: for fixed k, lanes read
  // consecutive addresses). Prep can afford 4 waves/SIMD.
  float w0c[DIM];
#pragma unroll
  for (int k = 0; k < DIM; ++k) w0c[k] = W0[k * DIM + lane];

  __syncthreads();

  // ---- Phase A: per-thread ns/nd, f64 chain (unchanged numerics) ----
  for (int r = blockIdx.x * 256 + tid; r < N_CELLS; r += gridDim.x * 256) {
    const float4* x4 = (const float4*)(x + (size_t)r * DIM);
    double s0 = 0.0, s1 = 0.0, d0 = 0.0, d1 = 0.0;
#pragma unroll
    for (int q = 0; q < DIM / 4; ++q) {
      float4 v = x4[q];
      double2 p0 = p_s[4 * q + 0], p1 = p_s[4 * q + 1];
      double2 p2 = p_s[4 * q + 2], p3 = p_s[4 * q + 3];
      s0 = fma((double)v.x, p0.x, s0); d0 = fma((double)v.x, p0.y, d0);
      s1 = fma((double)v.y, p1.x, s1); d1 = fma((double)v.y, p1.y, d1);
      s0 = fma((double)v.z, p2.x, s0); d0 = fma((double)v.z, p2.y, d0);
      s1 = fma((double)v.w, p3.x, s1); d1 = fma((double)v.w, p3.y, d1);
    }
    ns[r] = s0 + s1;
    nd[r] = d0 + d1;
  }

  // ---- Phase B: wave-per-row message = x @ W0 -> fp16 ----
  // Lane j computes message[r][j]. Row broadcast via per-wave LDS slot
  // (same-wave RAW, in-order DS — no barrier needed). Software-pipelined
  // row load.
  const int gw = blockIdx.x * 4 + wid;
  const int nwv = gridDim.x * 4;
  float v_c = 0.0f;
  if (gw < N_CELLS) v_c = x[(size_t)gw * DIM + lane];
  for (int r = gw; r < N_CELLS; r += nwv) {
    x_s[wid][lane] = v_c;
    const int rn = r + nwv;
    if (rn < N_CELLS) v_c = x[(size_t)rn * DIM + lane];
    float acc = 0.0f;
    const float4* xs4 = (const float4*)x_s[wid];
#pragma unroll
    for (int q = 0; q < DIM / 4; ++q) {
      float4 v = xs4[q];  // broadcast reads, conflict-free
      acc = fmaf(v.x, w0c[4 * q + 0], acc);
      acc = fmaf(v.y, w0c[4 * q + 1], acc);
      acc = fmaf(v.z, w0c[4 * q + 2], acc);
      acc = fmaf(v.w, w0c[4 * q + 3], acc);
    }
    m2[(size_t)r * DIM + lane] = __float2half(acc);  // keep cached (no NT)
  }
}

// Kernel B: 2 rows per wave-iter, software-pipelined as before, but now:
//   - gathers message rows (fp16) instead of x rows — output features come
//     straight out of the weighted sum: out[r][2sub..2sub+1] = relu(ax,ay).
//   - No W0 column cache, no h_s, no final GEMV phase.
//   - __launch_bounds__(256,8): target <=64 VGPR -> 8 waves/SIMD (2x the
//     previous 4) to hide L2/LLC gather latency.
__global__ __launch_bounds__(256, 8)
void gat_edges(const __half* __restrict__ m2,
               const int* __restrict__ ecol,
               const float* __restrict__ nv,
               const double* __restrict__ ns,
               const double* __restrict__ nd,
               float* __restrict__ out) {
  __shared__ __align__(16) float w_s[4][2][DEG];
  __shared__ __align__(16) int c_s[4][2][DEG];

  const int lane = threadIdx.x & 63;
  const int wid = threadIdx.x >> 6;
  const int half = lane >> 5;   // which row of the pair
  const int sub = lane & 31;    // edge index / feature-pair index

  const int gwave = blockIdx.x * 4 + wid;
  const int nwaves = gridDim.x * 4;
  const unsigned* xp = (const unsigned*)m2;

  // ---- pipeline preamble: prefetch iteration 0's scalars ----
  int col_c = 0; float nv_c = 0.0f; double nd_c = 0.0, ns_c = 0.0;
  if (gwave < NPAIRS) {
    const int eidx = 2 * gwave * DEG + lane;
    col_c = __builtin_nontemporal_load(ecol + eidx);
    nv_c = __builtin_nontemporal_load(nv + eidx);
    nd_c = nd[col_c];
    ns_c = ns[2 * gwave + half];
  }

  for (int p = gwave; p < NPAIRS; p += nwaves) {
    const int r0 = 2 * p;
    const int col = col_c;
    const float nvv = nv_c;

    // ---- e phase: fully register-resident ----
    double z = ns_c + nd_c;
    double e = (z >= 0.0) ? z : NEG_SLOPE * z;
    double rs = e;
#pragma unroll
    for (int m = 16; m >= 1; m >>= 1) rs += __shfl_xor(rs, m, 64);  // per-half
    w_s[wid][half][sub] = nvv * ((float)e / (float)rs);  // divide OK in f32
    c_s[wid][half][sub] = col;

    // ---- prefetch next iteration's col/nv/ns (independent loads) ----
    const int pn = p + nwaves;
    const int psafe = (pn < NPAIRS) ? pn : p;
    const int eidxn = 2 * psafe * DEG + lane;
    col_c = __builtin_nontemporal_load(ecol + eidxn);
    nv_c = __builtin_nontemporal_load(nv + eidxn);
    ns_c = ns[2 * psafe + half];

    // ---- gather message[2*sub..2*sub+1] over the half's 32 edges,
    //      2 x 16-deep independent-load batches ----
    const int* cs = c_s[wid][half];
    const float* wsp = w_s[wid][half];
    float ax = 0.0f, ay = 0.0f;
#pragma unroll
    for (int b = 0; b < DEG; b += 16) {
      unsigned pk[16];
#pragma unroll
      for (int i = 0; i < 16; ++i)
        pk[i] = xp[(size_t)cs[b + i] * (DIM / 2) + sub];
#pragma unroll
      for (int i = 0; i < 16; ++i) {
        float2 v = __half22float2(*(const __half2*)&pk[i]);
        float w = wsp[b + i];
        ax = fmaf(w, v.x, ax);
        ay = fmaf(w, v.y, ay);
      }
    }

    // ---- dependent prefetch: nd[col_next] (col_next landed during gather) ----
    nd_c = nd[col_c];

    // ---- output: features are the weighted sum directly ----
    float2 o = make_float2(fmaxf(ax, 0.0f), fmaxf(ay, 0.0f));
    union { float2 f; unsigned long long u; } cv; cv.f = o;
    __builtin_nontemporal_store(
        cv.u, (unsigned long long*)(out + (size_t)(r0 + half) * DIM + 2 * sub));
  }
}

extern "C" void kernel_launch(void* const* d_in, const int* in_sizes, int n_in,
                              void* d_out, int out_size, void* d_ws, size_t ws_size,
                              hipStream_t stream) {
  const float* x = (const float*)d_in[0];
  // d_in[1] = edge_rows: known structure repeat(arange(N_CELLS), DEG) — row = edge/DEG
  const int* ecol = (const int*)d_in[2];
  const float* nv = (const float*)d_in[3];
  const float* W0 = (const float*)d_in[4];
  const float* a0 = (const float*)d_in[5];
  float* out = (float*)d_out;

  // ws layout: m2 (6.4 MB fp16 message) | ns (400 KB f64) | nd (400 KB f64)
  __half* m2 = (__half*)d_ws;
  double* ns = (double*)((char*)d_ws + (size_t)N_CELLS * DIM * sizeof(__half));
  double* nd = ns + N_CELLS;

  hipLaunchKernelGGL(gat_prep, dim3(1024), dim3(256), 0, stream,
                     x, W0, a0, m2, ns, nd);
  // 2048 blocks * 4 waves = 8192 waves; 8 blocks/CU (32 waves/CU) if VGPR<=64.
  // Bulk does 3 iters/wave; 424 waves run a 4th (short tail).
  hipLaunchKernelGGL(gat_edges, dim3(2048), dim3(256), 0, stream,
                     m2, ecol, nv, ns, nd, out);
}

// Round 3
// 134.734 us; speedup vs baseline: 1.1935x; 1.1935x over previous
//
#include <hip/hip_runtime.h>
#include <hip/hip_fp16.h>

#define N_CELLS 50000
#define DEG 32
#define DIM 64
#define NEG_SLOPE 0.2
#define NPAIRS (N_CELLS / 2)

// Kernel A (wave-per-row, fused):
//   lane j of a wave owns column j.
//   - p_src[j] = (W0 @ a_src)[j], p_dst[j] = (W0 @ a_dst)[j] held as per-lane
//     f64 SCALARS (no arrays -> nothing for the spiller to evict).
//   - ns[r] = sum_j x[r][j] p_src[j], nd[r] likewise: f64 product + f64
//     __shfl_xor tree (order differs from the old sequential chain; f64 makes
//     the difference ~1e-16 rel, amplified ~1e4 by row_sum cancellation ->
//     ~1e-12: safe).
//   - message[r][j] = sum_k x[r][k] W0[k][j] with W0 column j in registers
//     (w0c hot every iteration -> register-resident), row broadcast via
//     per-wave LDS slot. Stored fp16 for the edge-kernel gathers.
// One pass over x (12.8 MB) instead of two + NO scratch (round-1 failure:
// VGPR_Count=64 proved w0c spilled; 105 MB WRITE_SIZE was scratch traffic).
__global__ __launch_bounds__(256, 4)
void gat_prep(const float* __restrict__ x,
              const float* __restrict__ W0,
              const float* __restrict__ a0,
              __half* __restrict__ m2,
              double* __restrict__ ns,
              double* __restrict__ nd) {
  __shared__ float x_s[4][DIM];  // per-wave row slot for the GEMV broadcast

  const int tid = threadIdx.x;
  const int lane = tid & 63;
  const int wid = tid >> 6;

  // ---- per-lane p_src/p_dst (f64 scalars): read W0 row `lane` ----
  double ps = 0.0, pd = 0.0;
  {
    const float4* w4 = (const float4*)(W0 + (size_t)lane * DIM);
#pragma unroll
    for (int q = 0; q < DIM / 4; ++q) {
      float4 w = w4[q];
      ps = fma((double)w.x, (double)a0[4 * q + 0], ps);
      ps = fma((double)w.y, (double)a0[4 * q + 1], ps);
      ps = fma((double)w.z, (double)a0[4 * q + 2], ps);
      ps = fma((double)w.w, (double)a0[4 * q + 3], ps);
      pd = fma((double)w.x, (double)a0[DIM + 4 * q + 0], pd);
      pd = fma((double)w.y, (double)a0[DIM + 4 * q + 1], pd);
      pd = fma((double)w.z, (double)a0[DIM + 4 * q + 2], pd);
      pd = fma((double)w.w, (double)a0[DIM + 4 * q + 3], pd);
    }
  }

  // ---- W0 column `lane` in registers (hot in every loop iteration) ----
  float w0c[DIM];
#pragma unroll
  for (int k = 0; k < DIM; ++k) w0c[k] = W0[(size_t)k * DIM + lane];

  const int gw = blockIdx.x * 4 + wid;
  const int nwv = gridDim.x * 4;

  // software-pipelined row load
  float v_c = 0.0f;
  if (gw < N_CELLS) v_c = x[(size_t)gw * DIM + lane];

  for (int r = gw; r < N_CELLS; r += nwv) {
    const float xv = v_c;
    x_s[wid][lane] = xv;  // same-wave RAW; in-order DS, no barrier needed

    const int rn = r + nwv;
    if (rn < N_CELLS) v_c = x[(size_t)rn * DIM + lane];

    // ---- ns/nd: f64 per-lane product + 64-lane xor-tree reduce ----
    double sj = (double)xv * ps;
    double dj = (double)xv * pd;
#pragma unroll
    for (int m = 32; m >= 1; m >>= 1) {
      sj += __shfl_xor(sj, m, 64);
      dj += __shfl_xor(dj, m, 64);
    }
    if (lane == 0) {
      ns[r] = sj;
      nd[r] = dj;
    }

    // ---- message GEMV: acc = sum_k x[r][k] * W0[k][lane] ----
    float acc = 0.0f;
    const float4* xs4 = (const float4*)x_s[wid];
#pragma unroll
    for (int q = 0; q < DIM / 4; ++q) {
      float4 v = xs4[q];  // broadcast reads, conflict-free
      acc = fmaf(v.x, w0c[4 * q + 0], acc);
      acc = fmaf(v.y, w0c[4 * q + 1], acc);
      acc = fmaf(v.z, w0c[4 * q + 2], acc);
      acc = fmaf(v.w, w0c[4 * q + 3], acc);
    }
    m2[(size_t)r * DIM + lane] = __float2half(acc);  // keep cached (no NT)
  }
}

// Kernel B (unchanged from round 1): 2 rows per wave-iter, software-pipelined;
// gathers fp16 message rows — output features come straight out of the
// weighted sum. No W0 work, no h_s staging, target 8 waves/SIMD.
__global__ __launch_bounds__(256, 8)
void gat_edges(const __half* __restrict__ m2,
               const int* __restrict__ ecol,
               const float* __restrict__ nv,
               const double* __restrict__ ns,
               const double* __restrict__ nd,
               float* __restrict__ out) {
  __shared__ __align__(16) float w_s[4][2][DEG];
  __shared__ __align__(16) int c_s[4][2][DEG];

  const int lane = threadIdx.x & 63;
  const int wid = threadIdx.x >> 6;
  const int half = lane >> 5;   // which row of the pair
  const int sub = lane & 31;    // edge index / feature-pair index

  const int gwave = blockIdx.x * 4 + wid;
  const int nwaves = gridDim.x * 4;
  const unsigned* xp = (const unsigned*)m2;

  // ---- pipeline preamble: prefetch iteration 0's scalars ----
  int col_c = 0; float nv_c = 0.0f; double nd_c = 0.0, ns_c = 0.0;
  if (gwave < NPAIRS) {
    const int eidx = 2 * gwave * DEG + lane;
    col_c = __builtin_nontemporal_load(ecol + eidx);
    nv_c = __builtin_nontemporal_load(nv + eidx);
    nd_c = nd[col_c];
    ns_c = ns[2 * gwave + half];
  }

  for (int p = gwave; p < NPAIRS; p += nwaves) {
    const int r0 = 2 * p;
    const int col = col_c;
    const float nvv = nv_c;

    // ---- e phase: fully register-resident ----
    double z = ns_c + nd_c;
    double e = (z >= 0.0) ? z : NEG_SLOPE * z;
    double rs = e;
#pragma unroll
    for (int m = 16; m >= 1; m >>= 1) rs += __shfl_xor(rs, m, 64);  // per-half
    w_s[wid][half][sub] = nvv * ((float)e / (float)rs);  // divide OK in f32
    c_s[wid][half][sub] = col;

    // ---- prefetch next iteration's col/nv/ns (independent loads) ----
    const int pn = p + nwaves;
    const int psafe = (pn < NPAIRS) ? pn : p;
    const int eidxn = 2 * psafe * DEG + lane;
    col_c = __builtin_nontemporal_load(ecol + eidxn);
    nv_c = __builtin_nontemporal_load(nv + eidxn);
    ns_c = ns[2 * psafe + half];

    // ---- gather message[2*sub..2*sub+1] over the half's 32 edges,
    //      2 x 16-deep independent-load batches ----
    const int* cs = c_s[wid][half];
    const float* wsp = w_s[wid][half];
    float ax = 0.0f, ay = 0.0f;
#pragma unroll
    for (int b = 0; b < DEG; b += 16) {
      unsigned pk[16];
#pragma unroll
      for (int i = 0; i < 16; ++i)
        pk[i] = xp[(size_t)cs[b + i] * (DIM / 2) + sub];
#pragma unroll
      for (int i = 0; i < 16; ++i) {
        float2 v = __half22float2(*(const __half2*)&pk[i]);
        float w = wsp[b + i];
        ax = fmaf(w, v.x, ax);
        ay = fmaf(w, v.y, ay);
      }
    }

    // ---- dependent prefetch: nd[col_next] (col_next landed during gather) ----
    nd_c = nd[col_c];

    // ---- output: features are the weighted sum directly ----
    float2 o = make_float2(fmaxf(ax, 0.0f), fmaxf(ay, 0.0f));
    union { float2 f; unsigned long long u; } cv; cv.f = o;
    __builtin_nontemporal_store(
        cv.u, (unsigned long long*)(out + (size_t)(r0 + half) * DIM + 2 * sub));
  }
}

extern "C" void kernel_launch(void* const* d_in, const int* in_sizes, int n_in,
                              void* d_out, int out_size, void* d_ws, size_t ws_size,
                              hipStream_t stream) {
  const float* x = (const float*)d_in[0];
  // d_in[1] = edge_rows: known structure repeat(arange(N_CELLS), DEG) — row = edge/DEG
  const int* ecol = (const int*)d_in[2];
  const float* nv = (const float*)d_in[3];
  const float* W0 = (const float*)d_in[4];
  const float* a0 = (const float*)d_in[5];
  float* out = (float*)d_out;

  // ws layout: m2 (6.4 MB fp16 message) | ns (400 KB f64) | nd (400 KB f64)
  __half* m2 = (__half*)d_ws;
  double* ns = (double*)((char*)d_ws + (size_t)N_CELLS * DIM * sizeof(__half));
  double* nd = ns + N_CELLS;

  // 1024 blocks * 4 waves = 4096 waves, ~12 rows/wave
  hipLaunchKernelGGL(gat_prep, dim3(1024), dim3(256), 0, stream,
                     x, W0, a0, m2, ns, nd);
  // 2048 blocks * 4 waves = 8192 waves; 8 blocks/CU (32 waves/CU) if VGPR<=64.
  hipLaunchKernelGGL(gat_edges, dim3(2048), dim3(256), 0, stream,
                     m2, ecol, nv, ns, nd, out);
}